// Round 6
// baseline (234.598 us; speedup 1.0000x reference)
//
#include <hip/hip_runtime.h>
#include <stdint.h>

#define K_CODES   8192
#define N_PIX     16384
#define D_DIM     64
#define EM_STRIDE 8193   // original embed row stride (K+1)
#define KSUB      4      // 512-code subtiles per block (k-persistence)
#define KGRP      4      // 8192 / (KSUB*512)
#define DCH       16     // d-chunk rows staged per barrier pair (32 KB)
#define OUT_QUANT 0
#define OUT_DMIN  1048576
#define OUT_IND   (1048576 + 16384)

// async global->LDS, 16B per lane, wave-uniform LDS base + lane*16 dest
__device__ __forceinline__ void gld_lds16(const float* g, float* l) {
    __builtin_amdgcn_global_load_lds(
        (const __attribute__((address_space(1))) uint32_t*)g,
        (__attribute__((address_space(3))) uint32_t*)l, 16, 0, 0);
}

// ---------------------------------------------------------------------------
// Kernel 1: per-code squared norms (stale -> +huge, never selected) and a
// stride-8192 copy of embed so tile staging can use aligned 16B loads.
// ---------------------------------------------------------------------------
__global__ __launch_bounds__(256)
void vq_prep(const float* __restrict__ embed,
             const int* __restrict__ cnt,
             float* __restrict__ ec,     // [64][8192]
             float* __restrict__ cn) {   // [8192]
    int k = blockIdx.x * 256 + threadIdx.x;
    float s = 0.f;
#pragma unroll
    for (int d = 0; d < D_DIM; ++d) {
        float v = embed[d * EM_STRIDE + k];
        ec[d * K_CODES + k] = v;
        s = fmaf(v, v, s);
    }
    cn[k] = (cnt[k] < 1) ? 1.0e30f : s;
}

// ---------------------------------------------------------------------------
// Kernel 2: fp32 distance GEMM + fused running argmin.
// 256 thr = 4 waves. Wave w owns 8 consecutive rows (x values wave-uniform
// -> scalar s_load path). Lane owns 8 codes: two stride-16B float4 groups
// (+0 / +256 floats) so both ds_read_b128 keep the conflict-free pattern.
// Per d-step: 1 s_load_dwordx8 + 2 ds_read_b128 feed 64 FMA instrs -- half
// the lgkm-event density per FMA of the previous version (the measured
// stall source: SMEM+LDS share lgkmcnt, SMEM returns out-of-order).
// e tile [16][512] = 32 KB, serially staged (measured faster than 2-phase).
// Block covers 32 rows x 2048 codes (4 subtiles), running argmin in regs.
// ---------------------------------------------------------------------------
__global__ __launch_bounds__(256, 4)
void vq_dist_tile(const float* __restrict__ x,     // [64][16384]
                  const float* __restrict__ ec,    // [64][8192]
                  const float* __restrict__ cn,    // [8192] masked norms
                  float* __restrict__ pmin,        // [KGRP][16384]
                  int*   __restrict__ pidx) {      // [KGRP][16384]
    __shared__ float es[DCH][512];

    const int nb  = blockIdx.x & 511;    // 512 row blocks (32 rows each)
    const int kg  = blockIdx.x >> 9;     // 4 k-groups of 2048 codes
    const int n0  = nb * 32;
    const int kgb = kg * (KSUB * 512);
    const int t    = threadIdx.x;
    const int lane = t & 63;
    const int w    = t >> 6;             // wave 0..3
    const int wu   = __builtin_amdgcn_readfirstlane(w);

    // x rows for this wave: n0 + wu*8 .. +7 (uniform across all 64 lanes)
    const float* __restrict__ xw = x + n0 + wu * 8;

    float acc[8][8];
    float bd[8];
    int   bix[8];
#pragma unroll
    for (int r = 0; r < 8; ++r) {
        bd[r] = 3.0e38f; bix[r] = 0;
#pragma unroll
        for (int c = 0; c < 8; ++c) acc[r][c] = 0.f;
    }

    for (int st = 0; st < KSUB; ++st) {
        const int k0 = kgb + st * 512;

        for (int ch = 0; ch < 4; ++ch) {
            const int d0 = ch * DCH;
            __syncthreads();             // previous e-chunk fully consumed
            // ---- stage e chunk [16][512]: 32 x 1KB instrs, 8 per wave ----
#pragma unroll
            for (int j = 0; j < 8; ++j) {
                int q  = j * 4 + w;      // 0..31
                int rr = q >> 1;         // chunk row 0..15
                int hh = q & 1;          // 256-float half
                gld_lds16(ec + (d0 + rr) * K_CODES + k0 + hh * 256 + lane * 4,
                          &es[0][0] + rr * 512 + hh * 256);
            }
            __syncthreads();             // vmcnt(0) drain + barrier
            // ---- compute: 16 d-steps, 64 FMA instrs each ----
            const float* esl = &es[0][0] + lane * 4;
            const float* xc  = xw + d0 * N_PIX;
#pragma unroll 2
            for (int d = 0; d < DCH; ++d) {
                float4 ea = *(const float4*)(esl + d * 512);
                float4 eb = *(const float4*)(esl + d * 512 + 256);
                const float* xr = xc + d * N_PIX;
                float x0 = xr[0], x1 = xr[1], x2 = xr[2], x3 = xr[3];
                float x4 = xr[4], x5 = xr[5], x6 = xr[6], x7 = xr[7];
                acc[0][0] = fmaf(x0, ea.x, acc[0][0]);
                acc[0][1] = fmaf(x0, ea.y, acc[0][1]);
                acc[0][2] = fmaf(x0, ea.z, acc[0][2]);
                acc[0][3] = fmaf(x0, ea.w, acc[0][3]);
                acc[0][4] = fmaf(x0, eb.x, acc[0][4]);
                acc[0][5] = fmaf(x0, eb.y, acc[0][5]);
                acc[0][6] = fmaf(x0, eb.z, acc[0][6]);
                acc[0][7] = fmaf(x0, eb.w, acc[0][7]);
                acc[1][0] = fmaf(x1, ea.x, acc[1][0]);
                acc[1][1] = fmaf(x1, ea.y, acc[1][1]);
                acc[1][2] = fmaf(x1, ea.z, acc[1][2]);
                acc[1][3] = fmaf(x1, ea.w, acc[1][3]);
                acc[1][4] = fmaf(x1, eb.x, acc[1][4]);
                acc[1][5] = fmaf(x1, eb.y, acc[1][5]);
                acc[1][6] = fmaf(x1, eb.z, acc[1][6]);
                acc[1][7] = fmaf(x1, eb.w, acc[1][7]);
                acc[2][0] = fmaf(x2, ea.x, acc[2][0]);
                acc[2][1] = fmaf(x2, ea.y, acc[2][1]);
                acc[2][2] = fmaf(x2, ea.z, acc[2][2]);
                acc[2][3] = fmaf(x2, ea.w, acc[2][3]);
                acc[2][4] = fmaf(x2, eb.x, acc[2][4]);
                acc[2][5] = fmaf(x2, eb.y, acc[2][5]);
                acc[2][6] = fmaf(x2, eb.z, acc[2][6]);
                acc[2][7] = fmaf(x2, eb.w, acc[2][7]);
                acc[3][0] = fmaf(x3, ea.x, acc[3][0]);
                acc[3][1] = fmaf(x3, ea.y, acc[3][1]);
                acc[3][2] = fmaf(x3, ea.z, acc[3][2]);
                acc[3][3] = fmaf(x3, ea.w, acc[3][3]);
                acc[3][4] = fmaf(x3, eb.x, acc[3][4]);
                acc[3][5] = fmaf(x3, eb.y, acc[3][5]);
                acc[3][6] = fmaf(x3, eb.z, acc[3][6]);
                acc[3][7] = fmaf(x3, eb.w, acc[3][7]);
                acc[4][0] = fmaf(x4, ea.x, acc[4][0]);
                acc[4][1] = fmaf(x4, ea.y, acc[4][1]);
                acc[4][2] = fmaf(x4, ea.z, acc[4][2]);
                acc[4][3] = fmaf(x4, ea.w, acc[4][3]);
                acc[4][4] = fmaf(x4, eb.x, acc[4][4]);
                acc[4][5] = fmaf(x4, eb.y, acc[4][5]);
                acc[4][6] = fmaf(x4, eb.z, acc[4][6]);
                acc[4][7] = fmaf(x4, eb.w, acc[4][7]);
                acc[5][0] = fmaf(x5, ea.x, acc[5][0]);
                acc[5][1] = fmaf(x5, ea.y, acc[5][1]);
                acc[5][2] = fmaf(x5, ea.z, acc[5][2]);
                acc[5][3] = fmaf(x5, ea.w, acc[5][3]);
                acc[5][4] = fmaf(x5, eb.x, acc[5][4]);
                acc[5][5] = fmaf(x5, eb.y, acc[5][5]);
                acc[5][6] = fmaf(x5, eb.z, acc[5][6]);
                acc[5][7] = fmaf(x5, eb.w, acc[5][7]);
                acc[6][0] = fmaf(x6, ea.x, acc[6][0]);
                acc[6][1] = fmaf(x6, ea.y, acc[6][1]);
                acc[6][2] = fmaf(x6, ea.z, acc[6][2]);
                acc[6][3] = fmaf(x6, ea.w, acc[6][3]);
                acc[6][4] = fmaf(x6, eb.x, acc[6][4]);
                acc[6][5] = fmaf(x6, eb.y, acc[6][5]);
                acc[6][6] = fmaf(x6, eb.z, acc[6][6]);
                acc[6][7] = fmaf(x6, eb.w, acc[6][7]);
                acc[7][0] = fmaf(x7, ea.x, acc[7][0]);
                acc[7][1] = fmaf(x7, ea.y, acc[7][1]);
                acc[7][2] = fmaf(x7, ea.z, acc[7][2]);
                acc[7][3] = fmaf(x7, ea.w, acc[7][3]);
                acc[7][4] = fmaf(x7, eb.x, acc[7][4]);
                acc[7][5] = fmaf(x7, eb.y, acc[7][5]);
                acc[7][6] = fmaf(x7, eb.z, acc[7][6]);
                acc[7][7] = fmaf(x7, eb.w, acc[7][7]);
            }
        }

        // ---- per-subtile epilogue: dist = cn - 2*dot, running argmin ----
        // lane's codes: half1 = k0+lane*4+c (c=0..3), half2 = +256 more.
        const int kb1 = k0 + lane * 4;
        const int kb2 = kb1 + 256;
        float4 cna = *(const float4*)(cn + kb1);
        float4 cnb = *(const float4*)(cn + kb2);
        float cnv[8] = {cna.x, cna.y, cna.z, cna.w,
                        cnb.x, cnb.y, cnb.z, cnb.w};
#pragma unroll
        for (int r = 0; r < 8; ++r) {
#pragma unroll
            for (int c = 0; c < 8; ++c) {    // ascending k order: strict <
                float dist = fmaf(-2.f, acc[r][c], cnv[c]);
                int   k    = (c < 4) ? (kb1 + c) : (kb2 + c - 4);
                if (dist < bd[r]) { bd[r] = dist; bix[r] = k; }
                acc[r][c] = 0.f;
            }
        }
    }

    // ---- once per block: butterfly-min across the 64 lanes, write ----
#pragma unroll
    for (int r = 0; r < 8; ++r) {
        float d = bd[r];
        int   i = bix[r];
#pragma unroll
        for (int m = 1; m < 64; m <<= 1) {
            float od = __shfl_xor(d, m, 64);
            int   oi = __shfl_xor(i, m, 64);
            if (od < d || (od == d && oi < i)) { d = od; i = oi; }
        }
        if (lane == 0) {
            pmin[kg * N_PIX + n0 + wu * 8 + r] = d;
            pidx[kg * N_PIX + n0 + wu * 8 + r] = i;
        }
    }
}

// ---------------------------------------------------------------------------
// Kernel 3: reduce 4 k-group partials per row, add ||x||^2, gather winning
// code column, write all three outputs.
// ---------------------------------------------------------------------------
__global__ __launch_bounds__(256)
void vq_finalize(const float* __restrict__ x,
                 const float* __restrict__ ec,
                 const float* __restrict__ pmin,
                 const int*   __restrict__ pidx,
                 float* __restrict__ out) {
    int n = blockIdx.x * 256 + threadIdx.x;   // 0..16383
    float best = 3.0e38f;
    int   bi   = 0x7fffffff;
#pragma unroll
    for (int kb = 0; kb < KGRP; ++kb) {
        float m = pmin[kb * N_PIX + n];
        int   i = pidx[kb * N_PIX + n];
        if (m < best || (m == best && i < bi)) { best = m; bi = i; }
    }
    float rn = 0.f;
#pragma unroll
    for (int d = 0; d < D_DIM; ++d) {
        float v = x[d * N_PIX + n];
        rn = fmaf(v, v, rn);
    }
    out[OUT_DMIN + n] = best + rn;
    out[OUT_IND  + n] = (float)bi;
#pragma unroll
    for (int d = 0; d < D_DIM; ++d)
        out[OUT_QUANT + d * N_PIX + n] = ec[d * K_CODES + bi];
}

// ---------------------------------------------------------------------------
extern "C" void kernel_launch(void* const* d_in, const int* in_sizes, int n_in,
                              void* d_out, int out_size, void* d_ws, size_t ws_size,
                              hipStream_t stream) {
    const float* x     = (const float*)d_in[0];   // [1,64,128,128]
    const float* embed = (const float*)d_in[1];   // [64,8193]
    const int*   cnt   = (const int*)d_in[2];     // [8192]
    float* out = (float*)d_out;

    // workspace layout
    float* ec   = (float*)d_ws;                                      // 2 MB
    float* cn   = (float*)((char*)d_ws + (size_t)2 * 1024 * 1024);   // 32 KB
    float* pmin = (float*)((char*)d_ws + (size_t)2 * 1024 * 1024 + 32768);
    int*   pidx = (int*)((char*)pmin + (size_t)KGRP * N_PIX * 4);

    vq_prep<<<K_CODES / 256, 256, 0, stream>>>(embed, cnt, ec, cn);
    vq_dist_tile<<<KGRP * 512, 256, 0, stream>>>(x, ec, cn, pmin, pidx);
    vq_finalize<<<N_PIX / 256, 256, 0, stream>>>(x, ec, pmin, pidx, out);
}